// Round 2
// baseline (1211.949 us; speedup 1.0000x reference)
//
#include <hip/hip_runtime.h>

#define B_ 16
#define NF_ 16
#define N_ 1024
#define D_ 128
#define S_ 8
#define NT 512
#define SCALE_ 0.08838834764831845f

// ---------------- LDS layouts ----------------
struct PA {                      // attention blocks (bid>=16)
  float X[64 * 128];             // swizzled: (j,k) -> j*128 + (((k>>2)^(j&7))<<2) + (k&3)
  float at[8 * 68];              // dots [s][j]
  float apt[64 * 12];            // attn*rinv transposed [j][s], pitch 12 (48B, 16B-aligned)
  float mean[64], rinv[64];
  float gqWs[1024];              // [s][128]
  float c0s[8], c1s[8];
  float pr[4 * 8 * 128];         // P partials [jh][s][d], 16 KB
};
struct PB {                      // per-batch GRU/FF blocks (bid<16)
  float h[8 * 132];
  float Pn[8 * 132];
  float buf[8 * 132];
  float hid[8 * 132];
  float hn[8 * 132];
  float gh[8 * 388];
  float gi[8 * 388];
  float part[4 * 8 * 128];       // 16 KB matvec partials
  float gI[128], bI[128], gS[128], bS[128], gF[128], bF[128];
  float ssp[8], mbp[8], qb[8];
  float red[32];
  float bqbkv;
};
union SMU { PA a; PB b; };

// ---- fence-free device-coherent accessors (proven pattern) ----
__device__ __forceinline__ float gload(const float* p) {
  return __hip_atomic_load(p, __ATOMIC_RELAXED, __HIP_MEMORY_SCOPE_AGENT);
}
__device__ __forceinline__ void gstore(float* p, float v) {
  __hip_atomic_store(p, v, __ATOMIC_RELAXED, __HIP_MEMORY_SCOPE_AGENT);
}
__device__ __forceinline__ void arrive(unsigned* c) {
  __syncthreads();
  if (threadIdx.x == 0) {
    __builtin_amdgcn_s_waitcnt(0);
    __hip_atomic_fetch_add(c, 1u, __ATOMIC_RELAXED, __HIP_MEMORY_SCOPE_AGENT);
  }
}
__device__ __forceinline__ void wait_for(unsigned* c, unsigned target) {
  if (threadIdx.x == 0) {
    while (__hip_atomic_load(c, __ATOMIC_RELAXED, __HIP_MEMORY_SCOPE_AGENT) < target)
      __builtin_amdgcn_s_sleep(1);
  }
  __syncthreads();
}
__device__ __forceinline__ float sigm(float x) { return 1.f / (1.f + __expf(-x)); }
__device__ __forceinline__ float tanh_f(float x) { return 1.f - 2.f / (1.f + __expf(2.f * x)); }

// 128x128 matvec (8 slot-vectors): pass-1 partials into part[kq][s][r].
// threads: r2 = t&63 (rows r2, r2+64), kq = (t>>6)&3 (k-chunk of 32), sh = t>>8 (slots sh*4..+3)
__device__ __forceinline__ void mv128_part(const float* __restrict__ W, const float* vec,
                                           float* part, int t) {
  int r2 = t & 63, kq = (t >> 6) & 3, sh = t >> 8;
  const float* w0 = W + r2 * 128 + kq * 32;
  const float* w1 = w0 + 64 * 128;
  float ac0[4] = {0.f, 0.f, 0.f, 0.f};
  float ac1[4] = {0.f, 0.f, 0.f, 0.f};
#pragma unroll
  for (int g = 0; g < 8; ++g) {
    float4 a = *(const float4*)(w0 + g * 4);
    float4 c = *(const float4*)(w1 + g * 4);
#pragma unroll
    for (int s4 = 0; s4 < 4; ++s4) {
      float4 v = *(const float4*)&vec[(sh * 4 + s4) * 132 + kq * 32 + g * 4];
      ac0[s4] += a.x * v.x + a.y * v.y + a.z * v.z + a.w * v.w;
      ac1[s4] += c.x * v.x + c.y * v.y + c.z * v.z + c.w * v.w;
    }
  }
#pragma unroll
  for (int s4 = 0; s4 < 4; ++s4) {
    part[(kq * 8 + sh * 4 + s4) * 128 + r2] = ac0[s4];
    part[(kq * 8 + sh * 4 + s4) * 128 + r2 + 64] = ac1[s4];
  }
}

// 384x128 matvec via 3x mv128_part; out pitch 388
__device__ void mv384(PB& B, const float* __restrict__ W, const float* __restrict__ bias,
                      const float* vec, float* out, int t) {
  for (int rb = 0; rb < 384; rb += 128) {
    mv128_part(W + (long)rb * 128, vec, B.part, t);
    __syncthreads();
#pragma unroll
    for (int i = 0; i < 2; ++i) {
      int idx = t + i * 512;
      int ss = idx >> 7, ddd = idx & 127;
      float o = bias[rb + ddd];
#pragma unroll
      for (int kq = 0; kq < 4; ++kq) o += B.part[kq * 1024 + idx];
      out[ss * 388 + rb + ddd] = o;
    }
    __syncthreads();
  }
}

// LN_sl(h) -> buf, then qW via Wqk fold -> publish gqW + c0/c1 (verified algebra, round 1)
__device__ void qchain(PB& B, const float* __restrict__ Wqk, const float* __restrict__ bqk,
                       const float* __restrict__ wqbk, float* gqW_g, float* cc_g, int b, int t) {
  int dd = t & 63, w = t >> 6;
  float v0 = B.h[w * 132 + dd], v1 = B.h[w * 132 + 64 + dd];
  float s1 = v0 + v1, s2 = v0 * v0 + v1 * v1;
#pragma unroll
  for (int off = 32; off; off >>= 1) { s1 += __shfl_down(s1, off); s2 += __shfl_down(s2, off); }
  s1 = __shfl(s1, 0); s2 = __shfl(s2, 0);
  float m = s1 * (1.f / 128.f);
  float inv = rsqrtf(s2 * (1.f / 128.f) - m * m + 1e-5f);
  float n0 = (v0 - m) * inv * B.gS[dd] + B.bS[dd];
  float n1 = (v1 - m) * inv * B.gS[64 + dd] + B.bS[64 + dd];
  B.buf[w * 132 + dd] = n0; B.buf[w * 132 + 64 + dd] = n1;
  float qp = wqbk[dd] * n0 + wqbk[64 + dd] * n1;
#pragma unroll
  for (int off = 32; off; off >>= 1) qp += __shfl_down(qp, off);
  if (dd == 0) B.qb[w] = qp + B.bqbkv;
  __syncthreads();
  mv128_part(Wqk, B.buf, B.part, t);
  __syncthreads();
  {
    int ddd = t & 127, s0 = t >> 7;
    float q0 = bqk[ddd], q1 = bqk[ddd];
#pragma unroll
    for (int kq = 0; kq < 4; ++kq) {
      q0 += B.part[kq * 1024 + s0 * 128 + ddd];
      q1 += B.part[kq * 1024 + (s0 + 4) * 128 + ddd];
    }
    float g0 = B.gI[ddd] * q0, g1 = B.gI[ddd] * q1;
    gstore(&gqW_g[b * 1024 + s0 * 128 + ddd], g0);
    gstore(&gqW_g[b * 1024 + (s0 + 4) * 128 + ddd], g1);
    float c1a = g0, c1b = g1, c0a = B.bI[ddd] * q0, c0b = B.bI[ddd] * q1;
#pragma unroll
    for (int off = 32; off; off >>= 1) {
      c1a += __shfl_down(c1a, off); c1b += __shfl_down(c1b, off);
      c0a += __shfl_down(c0a, off); c0b += __shfl_down(c0b, off);
    }
    if ((t & 63) == 0) {
      int wv = t >> 6;
      B.red[wv * 4 + 0] = c1a; B.red[wv * 4 + 1] = c1b;
      B.red[wv * 4 + 2] = c0a; B.red[wv * 4 + 3] = c0b;
    }
  }
  __syncthreads();
  if (t < 8) {
    int u = t & 3, hi = t >> 2;
    float c1 = B.red[(2 * u) * 4 + hi] + B.red[(2 * u + 1) * 4 + hi];
    float c0 = B.red[(2 * u) * 4 + 2 + hi] + B.red[(2 * u + 1) * 4 + 2 + hi] + B.qb[t];
    gstore(&cc_g[b * 16 + t], c1);
    gstore(&cc_g[b * 16 + 8 + t], c0);
  }
}

// one-shot folds (verified round 1): Wiv=Wih@Wv, bihv=Wih@bv+bih, Wqk, bqk, wqbk, bqbk
__global__ __launch_bounds__(128) void precomp(
    const float* __restrict__ Wih, const float* __restrict__ bih,
    const float* __restrict__ Wv, const float* __restrict__ bv,
    const float* __restrict__ Wq, const float* __restrict__ bq,
    const float* __restrict__ Wk, const float* __restrict__ bk,
    float* Wiv, float* bihv, float* Wqk, float* bqk, float* wqbk, float* bqbk) {
  __shared__ float r2[2];
  int r = blockIdx.x, t = threadIdx.x;
  if (r < 384) {
    float acc = 0.f;
#pragma unroll 8
    for (int k = 0; k < 128; ++k) acc += Wih[r * 128 + k] * Wv[k * 128 + t];
    Wiv[r * 128 + t] = acc;
    float p = Wih[r * 128 + t] * bv[t];
#pragma unroll
    for (int off = 32; off; off >>= 1) p += __shfl_down(p, off);
    if ((t & 63) == 0) r2[t >> 6] = p;
    __syncthreads();
    if (t == 0) bihv[r] = r2[0] + r2[1] + bih[r];
  } else {
    int c = r - 384;
    float acc = 0.f;
#pragma unroll 8
    for (int dd = 0; dd < 128; ++dd) acc += Wk[dd * 128 + c] * Wq[dd * 128 + t];
    Wqk[c * 128 + t] = acc;
    float p = Wk[t * 128 + c] * bq[t];
#pragma unroll
    for (int off = 32; off; off >>= 1) p += __shfl_down(p, off);
    if ((t & 63) == 0) r2[t >> 6] = p;
    __syncthreads();
    if (t == 0) bqk[c] = r2[0] + r2[1];
    if (c == 0) {
      float a2 = 0.f;
#pragma unroll 8
      for (int dd = 0; dd < 128; ++dd) a2 += Wq[dd * 128 + t] * bk[dd];
      wqbk[t] = a2;
      float p2 = bq[t] * bk[t];
#pragma unroll
      for (int off = 32; off; off >>= 1) p2 += __shfl_down(p2, off);
      __syncthreads();
      if ((t & 63) == 0) r2[t >> 6] = p2;
      __syncthreads();
      if (t == 0) bqbk[0] = r2[0] + r2[1];
    }
  }
}

__global__ __launch_bounds__(NT, 4) void slot_ab(
    const float* __restrict__ x, const float* __restrict__ slots_init,
    const float* __restrict__ Whh, const float* __restrict__ bhh,
    const float* __restrict__ W1, const float* __restrict__ b1,
    const float* __restrict__ W2, const float* __restrict__ b2,
    const float* __restrict__ g_in, const float* __restrict__ be_in,
    const float* __restrict__ g_sl, const float* __restrict__ be_sl,
    const float* __restrict__ g_ff, const float* __restrict__ be_ff,
    const float* __restrict__ Wiv, const float* __restrict__ bihv,
    const float* __restrict__ Wqk, const float* __restrict__ bqk,
    const float* __restrict__ wqbk, const float* __restrict__ bqbk,
    float* out_slots, float* out_attn,
    unsigned* cntA, unsigned* cntB,
    float* gqW_g, float* cc_g, float* Ppart, float* Spart) {
  __shared__ __align__(16) SMU sm;
  int t = threadIdx.x, bid = blockIdx.x;

  if (bid >= 16) {
    // ===================== A-block: (batch b, 64-row tile) =====================
    int ab = bid - 16;
    int b = ab >> 4, tile = ab & 15;
    unsigned* cA = cntA + (b << 6);
    unsigned* cB = cntB + (b << 6);
    int s = t >> 6, j = t & 63;
    const float* xb = x + (long)b * NF_ * N_ * D_;
    float4 pf[4];
    {
      const float* xs = xb + (long)tile * 64 * D_;
#pragma unroll
      for (int i = 0; i < 4; ++i) {
        int ch = t + i * 512;
        pf[i] = *(const float4*)(xs + (ch >> 5) * 128 + (ch & 31) * 4);
      }
    }
    for (int it = 0; it <= 16; ++it) {
      int f = (it == 0) ? 0 : it - 1;
      int wo = it > 0;
      // stage X (swizzled)  — overlaps with B's previous-frame chain
#pragma unroll
      for (int i = 0; i < 4; ++i) {
        int ch = t + i * 512;
        int jr = ch >> 5, kg = ch & 31;
        *(float4*)&sm.a.X[jr * 128 + ((kg ^ (jr & 7)) << 2)] = pf[i];
      }
      __syncthreads();
      // row stats (sum over permuted groups is permutation-invariant)
      {
        int r = t >> 3, p8 = t & 7;
        float s1 = 0.f, s2 = 0.f;
#pragma unroll
        for (int i = 0; i < 4; ++i) {
          float4 v = *(const float4*)&sm.a.X[r * 128 + (p8 * 4 + i) * 4];
          s1 += v.x + v.y + v.z + v.w;
          s2 += v.x * v.x + v.y * v.y + v.z * v.z + v.w * v.w;
        }
        s1 += __shfl_down(s1, 1); s2 += __shfl_down(s2, 1);
        s1 += __shfl_down(s1, 2); s2 += __shfl_down(s2, 2);
        s1 += __shfl_down(s1, 4); s2 += __shfl_down(s2, 4);
        if (p8 == 0) {
          float m = s1 * (1.f / 128.f);
          sm.a.mean[r] = m;
          sm.a.rinv[r] = rsqrtf(s2 * (1.f / 128.f) - m * m + 1e-5f);
        }
      }
      wait_for(cB, (unsigned)(it + 1));
      sm.a.gqWs[t] = gload(&gqW_g[b * 1024 + t]);
      sm.a.gqWs[t + 512] = gload(&gqW_g[b * 1024 + 512 + t]);
      if (t < 8) sm.a.c1s[t] = gload(&cc_g[b * 16 + t]);
      else if (t < 16) sm.a.c0s[t - 8] = gload(&cc_g[b * 16 + t]);
      __syncthreads();
      // dots with LN fold (b128 conflict-free X, uniform q broadcasts)
      {
        const float* qr = sm.a.gqWs + s * 128;
        float acc = 0.f;
#pragma unroll
        for (int k4 = 0; k4 < 32; ++k4) {
          float4 q4 = *(const float4*)&qr[k4 * 4];
          float4 x4 = *(const float4*)&sm.a.X[j * 128 + ((k4 ^ (j & 7)) << 2)];
          acc += q4.x * x4.x + q4.y * x4.y + q4.z * x4.z + q4.w * x4.w;
        }
        float val = (acc - sm.a.mean[j] * sm.a.c1s[s]) * sm.a.rinv[j] + sm.a.c0s[s];
        sm.a.at[s * 68 + j] = val * SCALE_;
      }
      __syncthreads();
      if (t < 64) {  // softmax over slots per column j=t
        float vv[8], mx = -1e30f;
#pragma unroll
        for (int ss = 0; ss < 8; ++ss) { vv[ss] = sm.a.at[ss * 68 + t]; mx = fmaxf(mx, vv[ss]); }
        float sum = 0.f;
#pragma unroll
        for (int ss = 0; ss < 8; ++ss) { vv[ss] = __expf(vv[ss] - mx); sum += vv[ss]; }
        float rr = 1.f / sum;
        float m = sm.a.mean[t], riv = sm.a.rinv[t];
        float a1[8], a2[8];
#pragma unroll
        for (int ss = 0; ss < 8; ++ss) {
          float attn = vv[ss] * rr + 1e-8f;
          if (wo) out_attn[(((long)b * NF_ + f) * S_ + ss) * N_ + tile * 64 + t] = attn;
          sm.a.apt[t * 12 + ss] = attn * riv;
          a1[ss] = attn; a2[ss] = attn * m * riv;
        }
#pragma unroll
        for (int off = 32; off; off >>= 1) {
#pragma unroll
          for (int ss = 0; ss < 8; ++ss) {
            a1[ss] += __shfl_down(a1[ss], off);
            a2[ss] += __shfl_down(a2[ss], off);
          }
        }
        if (t == 0) {
          float* Sp = Spart + (b * 16 + tile) * 16;
#pragma unroll
          for (int ss = 0; ss < 8; ++ss) { gstore(&Sp[ss], a1[ss]); gstore(&Sp[8 + ss], a2[ss]); }
        }
      }
      __syncthreads();
      // P partials over the tile's 64 rows (raw X; ap = attn*rinv; fold verified)
      {
        int dd = t & 127, jh = t >> 7;
        int dg = dd >> 2, dr = dd & 3;
        float acc[8] = {0.f, 0.f, 0.f, 0.f, 0.f, 0.f, 0.f, 0.f};
#pragma unroll
        for (int ji = 0; ji < 16; ++ji) {
          int jj = jh * 16 + ji;
          float xv = sm.a.X[jj * 128 + ((dg ^ (jj & 7)) << 2) + dr];
          float4 apa = *(const float4*)&sm.a.apt[jj * 12];
          float4 apb = *(const float4*)&sm.a.apt[jj * 12 + 4];
          acc[0] += xv * apa.x; acc[1] += xv * apa.y; acc[2] += xv * apa.z; acc[3] += xv * apa.w;
          acc[4] += xv * apb.x; acc[5] += xv * apb.y; acc[6] += xv * apb.z; acc[7] += xv * apb.w;
        }
#pragma unroll
        for (int ss = 0; ss < 8; ++ss) sm.a.pr[jh * 1024 + ss * 128 + dd] = acc[ss];
      }
      __syncthreads();
      {
        float* Pp = Ppart + (long)(b * 16 + tile) * 1024;
#pragma unroll
        for (int i = 0; i < 2; ++i) {
          int idx = t + i * 512;
          float v = sm.a.pr[idx] + sm.a.pr[1024 + idx] + sm.a.pr[2048 + idx] + sm.a.pr[3072 + idx];
          gstore(&Pp[idx], v);
        }
      }
      arrive(cA);
      if (it < 16) {  // prefetch next frame while B runs
        const float* xs = xb + ((long)it * N_ + tile * 64) * D_;
#pragma unroll
        for (int i = 0; i < 4; ++i) {
          int ch = t + i * 512;
          pf[i] = *(const float4*)(xs + (ch >> 5) * 128 + (ch & 31) * 4);
        }
      }
    }
  } else {
    // ===================== B-block: batch bid, all 8 slots =====================
    int b = bid;
    unsigned* cA = cntA + (b << 6);
    unsigned* cB = cntB + (b << 6);
    PB& B = sm.b;
    int dd64 = t & 63, w = t >> 6;
    if (t < 128) {
      B.gI[t] = g_in[t];  B.bI[t] = be_in[t];
      B.gS[t] = g_sl[t];  B.bS[t] = be_sl[t];
      B.gF[t] = g_ff[t];  B.bF[t] = be_ff[t];
    }
    if (t == 0) B.bqbkv = bqbk[0];
#pragma unroll
    for (int i = 0; i < 2; ++i) {
      int idx = t + i * 512;
      int ss = idx >> 7, ddd = idx & 127;
      B.h[ss * 132 + ddd] = slots_init[ss * 128 + ddd];
    }
    __syncthreads();
    qchain(B, Wqk, bqk, wqbk, gqW_g, cc_g, b, t);
    arrive(cB);
    mv384(B, Whh, bhh, B.h, B.gh, t);  // gh for iteration 0, off critical path

    for (int it = 0; it <= 16; ++it) {
      int f = it - 1;
      int wo = it > 0;
      wait_for(cA, 16u * (it + 1));
      // gather Spart (t<128) and Ppart partials (all threads), then Pn
      if (t < 128) {
        int ss = t >> 4, tl = t & 15;
        float sv = gload(&Spart[(b * 16 + tl) * 16 + ss]);
        float mv = gload(&Spart[(b * 16 + tl) * 16 + 8 + ss]);
        sv += __shfl_down(sv, 8); mv += __shfl_down(mv, 8);
        sv += __shfl_down(sv, 4); mv += __shfl_down(mv, 4);
        sv += __shfl_down(sv, 2); mv += __shfl_down(mv, 2);
        sv += __shfl_down(sv, 1); mv += __shfl_down(mv, 1);
        if (tl == 0) { B.ssp[ss] = sv; B.mbp[ss] = mv; }
      }
      float u0 = 0.f, u1 = 0.f;
      {
        const float* Pp0 = Ppart + (long)b * 16 * 1024;
#pragma unroll
        for (int tl = 0; tl < 16; ++tl) u0 += gload(&Pp0[tl * 1024 + t]);
#pragma unroll
        for (int tl = 0; tl < 16; ++tl) u1 += gload(&Pp0[tl * 1024 + 512 + t]);
      }
      __syncthreads();
      {
        int ss0 = t >> 7, dd0 = t & 127;
        float inv0 = 1.f / B.ssp[ss0];
        B.Pn[ss0 * 132 + dd0] = B.gI[dd0] * (u0 - B.mbp[ss0]) * inv0 + B.bI[dd0];
        int idx = t + 512;
        int ss1 = idx >> 7, dd1 = idx & 127;
        float inv1 = 1.f / B.ssp[ss1];
        B.Pn[ss1 * 132 + dd1] = B.gI[dd1] * (u1 - B.mbp[ss1]) * inv1 + B.bI[dd1];
      }
      __syncthreads();
      // gi = Wiv @ Pn + bihv  (Wv fold verified)
      mv384(B, Wiv, bihv, B.Pn, B.gi, t);
      // gates -> hn
#pragma unroll
      for (int i = 0; i < 2; ++i) {
        int idx = t + i * 512;
        int ss = idx >> 7, ddd = idx & 127;
        float gr = sigm(B.gi[ss * 388 + ddd] + B.gh[ss * 388 + ddd]);
        float gz = sigm(B.gi[ss * 388 + 128 + ddd] + B.gh[ss * 388 + 128 + ddd]);
        float gn = tanh_f(B.gi[ss * 388 + 256 + ddd] + gr * B.gh[ss * 388 + 256 + ddd]);
        B.hn[ss * 132 + ddd] = (1.f - gz) * gn + gz * B.h[ss * 132 + ddd];
      }
      __syncthreads();
      // LN_ff per-wave (wave = slot)
      {
        float v0 = B.hn[w * 132 + dd64], v1 = B.hn[w * 132 + 64 + dd64];
        float s1 = v0 + v1, s2 = v0 * v0 + v1 * v1;
#pragma unroll
        for (int off = 32; off; off >>= 1) { s1 += __shfl_down(s1, off); s2 += __shfl_down(s2, off); }
        s1 = __shfl(s1, 0); s2 = __shfl(s2, 0);
        float m = s1 * (1.f / 128.f);
        float inv = rsqrtf(s2 * (1.f / 128.f) - m * m + 1e-5f);
        B.buf[w * 132 + dd64] = (v0 - m) * inv * B.gF[dd64] + B.bF[dd64];
        B.buf[w * 132 + 64 + dd64] = (v1 - m) * inv * B.gF[64 + dd64] + B.bF[64 + dd64];
      }
      __syncthreads();
      // hid = relu(W1 @ buf + b1)
      mv128_part(W1, B.buf, B.part, t);
      __syncthreads();
#pragma unroll
      for (int i = 0; i < 2; ++i) {
        int idx = t + i * 512;
        int ss = idx >> 7, ddd = idx & 127;
        float o = b1[ddd];
#pragma unroll
        for (int kq = 0; kq < 4; ++kq) o += B.part[kq * 1024 + idx];
        B.hid[ss * 132 + ddd] = fmaxf(o, 0.f);
      }
      __syncthreads();
      // sn = hn + W2 @ hid + b2 -> h, out
      mv128_part(W2, B.hid, B.part, t);
      __syncthreads();
#pragma unroll
      for (int i = 0; i < 2; ++i) {
        int idx = t + i * 512;
        int ss = idx >> 7, ddd = idx & 127;
        float o = b2[ddd];
#pragma unroll
        for (int kq = 0; kq < 4; ++kq) o += B.part[kq * 1024 + idx];
        float sn = B.hn[ss * 132 + ddd] + o;
        B.h[ss * 132 + ddd] = sn;
        if (wo) out_slots[(((long)b * NF_ + f) * S_ + ss) * D_ + ddd] = sn;
      }
      __syncthreads();
      if (it < 16) {
        qchain(B, Wqk, bqk, wqbk, gqW_g, cc_g, b, t);   // publish next qW ASAP
        arrive(cB);
        mv384(B, Whh, bhh, B.h, B.gh, t);               // gh for next frame, off path
      }
    }
  }
}

extern "C" void kernel_launch(void* const* d_in, const int* in_sizes, int n_in,
                              void* d_out, int out_size, void* d_ws, size_t ws_size,
                              hipStream_t stream) {
  const float* inputs     = (const float*)d_in[0];
  const float* slots_init = (const float*)d_in[1];
  const float* Wq  = (const float*)d_in[2];
  const float* bq  = (const float*)d_in[3];
  const float* Wk  = (const float*)d_in[4];
  const float* bk  = (const float*)d_in[5];
  const float* Wv  = (const float*)d_in[6];
  const float* bv  = (const float*)d_in[7];
  const float* W1  = (const float*)d_in[8];
  const float* b1  = (const float*)d_in[9];
  const float* W2  = (const float*)d_in[10];
  const float* b2  = (const float*)d_in[11];
  const float* Wih = (const float*)d_in[12];
  const float* Whh = (const float*)d_in[13];
  const float* bih = (const float*)d_in[14];
  const float* bhh = (const float*)d_in[15];
  const float* g_in  = (const float*)d_in[16];
  const float* be_in = (const float*)d_in[17];
  const float* g_sl  = (const float*)d_in[18];
  const float* be_sl = (const float*)d_in[19];
  const float* g_ff  = (const float*)d_in[20];
  const float* be_ff = (const float*)d_in[21];

  float* out_slots = (float*)d_out;
  float* out_attn  = out_slots + (size_t)B_ * NF_ * S_ * D_;

  char* ws = (char*)d_ws;
  unsigned* cntA = (unsigned*)ws;                       // 16 counters, 256B apart
  unsigned* cntB = (unsigned*)(ws + 4096);
  float* Wiv   = (float*)(ws + 8192);                   // 384x128 = 196608
  float* bihv  = (float*)(ws + 204800);                 // 1536
  float* WqkW  = (float*)(ws + 206336);                 // 65536
  float* bqk   = (float*)(ws + 271872);                 // 512
  float* wqbk  = (float*)(ws + 272384);                 // 512
  float* bqbk  = (float*)(ws + 272896);                 // 256
  float* gqW_g = (float*)(ws + 273152);                 // 16*1024*4 = 65536
  float* cc_g  = (float*)(ws + 338688);                 // 1024
  float* Ppart = (float*)(ws + 339712);                 // 16*16*1024*4 = 1 MB
  float* Spart = (float*)(ws + 1388288);                // 16 KB

  hipMemsetAsync(d_ws, 0, 8192, stream);  // zero counters (graph-capturable)

  precomp<<<512, 128, 0, stream>>>(Wih, bih, Wv, bv, Wq, bq, Wk, bk,
                                   Wiv, bihv, WqkW, bqk, wqbk, bqbk);
  slot_ab<<<272, NT, 0, stream>>>(inputs, slots_init, Whh, bhh, W1, b1, W2, b2,
      g_in, be_in, g_sl, be_sl, g_ff, be_ff, Wiv, bihv, WqkW, bqk, wqbk, bqbk,
      out_slots, out_attn, cntA, cntB, gqW_g, cc_g, Ppart, Spart);
}

// Round 3
// 716.850 us; speedup vs baseline: 1.6907x; 1.6907x over previous
//
#include <hip/hip_runtime.h>

#define B_ 16
#define NF_ 16
#define N_ 1024
#define D_ 128
#define S_ 8
#define SCALE_ 0.08838834764831845f
#define NB 256
#define NT 512

struct SmemA {
  float Xt[64 * 132];       // normalized in place; pitch 132 -> 16B-aligned rows, <=2-way banks
  float qWs[1024];
  float at[512];
  float rowsum[64], rowsum2[64];
  float qbs[8];
};
struct SmemB {               // per-(b,s) phase-B scratch
  float Pk[128];
  float gh[384];
  float gi[384];             // giraw = Wiv@Pk (scale + bias applied at gate stage)
  float hn[128], buf[128], hid[128], nrm[128];
  float red[8];
  float ssm;
};
union Smem { SmemA a; SmemB b; };

// ---- fence-free device-coherent accessors (sc1 ops; proven in 612us baseline) ----
__device__ __forceinline__ float gload(const float* p) {
  return __hip_atomic_load(p, __ATOMIC_RELAXED, __HIP_MEMORY_SCOPE_AGENT);
}
__device__ __forceinline__ void gstore(float* p, float v) {
  __hip_atomic_store(p, v, __ATOMIC_RELAXED, __HIP_MEMORY_SCOPE_AGENT);
}

__device__ __forceinline__ void arrive(unsigned* c) {
  __syncthreads();
  if (threadIdx.x == 0) {
    __builtin_amdgcn_s_waitcnt(0);
    __hip_atomic_fetch_add(c, 1u, __ATOMIC_RELAXED, __HIP_MEMORY_SCOPE_AGENT);
  }
}
__device__ __forceinline__ void wait_for(unsigned* c, unsigned target) {
  if (threadIdx.x == 0) {
    while (__hip_atomic_load(c, __ATOMIC_RELAXED, __HIP_MEMORY_SCOPE_AGENT) < target)
      __builtin_amdgcn_s_sleep(1);
  }
  __syncthreads();
}

// acc += dot(fp32 row of 128, fp32 x[128] in LDS); acc starts at bias
__device__ __forceinline__ float dot128f(const float* __restrict__ wrow, const float* x, float acc) {
  const float4* w = (const float4*)wrow;
#pragma unroll
  for (int i = 0; i < 32; ++i) {
    float4 v = w[i];
    const float4 xv = *(const float4*)(x + i * 4);
    acc += v.x * xv.x + v.y * xv.y + v.z * xv.z + v.w * xv.w;
  }
  return acc;
}

// Block-wide mean / rsqrt(var+eps) over 128 values held by threads t<128. ALL threads call.
__device__ __forceinline__ void stats128(float v, int t, float* red, float& m, float& inv, float eps) {
  __syncthreads();
  float s = (t < 128) ? v : 0.f;
  float s2 = (t < 128) ? v * v : 0.f;
#pragma unroll
  for (int off = 32; off; off >>= 1) { s += __shfl_down(s, off); s2 += __shfl_down(s2, off); }
  if (t == 0)  { red[0] = s; red[2] = s2; }
  if (t == 64) { red[1] = s; red[3] = s2; }
  __syncthreads();
  m = (red[0] + red[1]) * (1.f / 128.f);
  float var = (red[2] + red[3]) * (1.f / 128.f) - m * m;
  inv = rsqrtf(var + 1e-5f);
}

__device__ __forceinline__ float sigm(float x) { return 1.f / (1.f + __expf(-x)); }
__device__ __forceinline__ float tanh_f(float x) { return 1.f - 2.f / (1.f + __expf(2.f * x)); }

// slot (LDS,128) -> LN_sl -> qW = Wqk@nrm + bqk (fold, verified r1/r2); qb = wqbk.nrm + bqbk
__device__ void q_project(SmemB& Bm, const float* slot,
    const float* __restrict__ g_sl, const float* __restrict__ be_sl,
    const float* __restrict__ Wqk, const float* __restrict__ bqk,
    const float* __restrict__ wqbk, const float* __restrict__ bqbk,
    float* qW_g, float* qb_g, int bs) {
  int t = threadIdx.x;
  float m, inv;
  float sv = (t < 128) ? slot[t] : 0.f;
  stats128(sv, t, Bm.red, m, inv, 1e-5f);
  if (t < 128) Bm.nrm[t] = (sv - m) * inv * g_sl[t] + be_sl[t];
  __syncthreads();
  if (t < 128) {
    float a = dot128f(Wqk + t * 128, Bm.nrm, bqk[t]);
    gstore(&qW_g[bs * 128 + t], a);
    float p = wqbk[t] * Bm.nrm[t];
#pragma unroll
    for (int off = 32; off; off >>= 1) p += __shfl_down(p, off);
    if (t == 0)  Bm.red[4] = p;
    if (t == 64) Bm.red[5] = p;
  }
  __syncthreads();
  if (t == 0) gstore(&qb_g[bs], Bm.red[4] + Bm.red[5] + bqbk[0]);
}

// one-shot algebraic folds (verified rounds 1-2): Wiv=Wih@Wv, bihv=Wih@bv+bih,
// Wqk=Wk^T@Wq, bqk=Wk^T@bq, wqbk=Wq^T@bk, bqbk=bq.bk
__global__ __launch_bounds__(128) void precomp(
    const float* __restrict__ Wih, const float* __restrict__ bih,
    const float* __restrict__ Wv, const float* __restrict__ bv,
    const float* __restrict__ Wq, const float* __restrict__ bq,
    const float* __restrict__ Wk, const float* __restrict__ bk,
    float* Wiv, float* bihv, float* Wqk, float* bqk, float* wqbk, float* bqbk) {
  __shared__ float r2[2];
  int r = blockIdx.x, t = threadIdx.x;
  if (r < 384) {
    float acc = 0.f;
#pragma unroll 8
    for (int k = 0; k < 128; ++k) acc += Wih[r * 128 + k] * Wv[k * 128 + t];
    Wiv[r * 128 + t] = acc;
    float p = Wih[r * 128 + t] * bv[t];
#pragma unroll
    for (int off = 32; off; off >>= 1) p += __shfl_down(p, off);
    if ((t & 63) == 0) r2[t >> 6] = p;
    __syncthreads();
    if (t == 0) bihv[r] = r2[0] + r2[1] + bih[r];
  } else {
    int c = r - 384;
    float acc = 0.f;
#pragma unroll 8
    for (int dd = 0; dd < 128; ++dd) acc += Wk[dd * 128 + c] * Wq[dd * 128 + t];
    Wqk[c * 128 + t] = acc;
    float p = Wk[t * 128 + c] * bq[t];
#pragma unroll
    for (int off = 32; off; off >>= 1) p += __shfl_down(p, off);
    if ((t & 63) == 0) r2[t >> 6] = p;
    __syncthreads();
    if (t == 0) bqk[c] = r2[0] + r2[1];
    if (c == 0) {
      float a2 = 0.f;
#pragma unroll 8
      for (int dd = 0; dd < 128; ++dd) a2 += Wq[dd * 128 + t] * bk[dd];
      wqbk[t] = a2;
      float p2 = bq[t] * bk[t];
#pragma unroll
      for (int off = 32; off; off >>= 1) p2 += __shfl_down(p2, off);
      __syncthreads();
      if ((t & 63) == 0) r2[t >> 6] = p2;
      __syncthreads();
      if (t == 0) bqbk[0] = r2[0] + r2[1];
    }
  }
}

__global__ __launch_bounds__(NT) void slot_persist(
    const float* __restrict__ x, const float* __restrict__ slots_init,
    const float* __restrict__ Whh, const float* __restrict__ bhh,
    const float* __restrict__ W1, const float* __restrict__ b1,
    const float* __restrict__ W2, const float* __restrict__ b2,
    const float* __restrict__ g_in, const float* __restrict__ be_in,
    const float* __restrict__ g_sl, const float* __restrict__ be_sl,
    const float* __restrict__ g_ff, const float* __restrict__ be_ff,
    const float* __restrict__ Wiv, const float* __restrict__ bihv,
    const float* __restrict__ Wqk, const float* __restrict__ bqk,
    const float* __restrict__ wqbk, const float* __restrict__ bqbk,
    float* out_slots, float* out_attn,
    unsigned* cntA, unsigned* cntB,
    float* qW_g, float* qb_g, float* P_part, float* S_part) {
  __shared__ __align__(16) Smem sm;
  __shared__ __align__(16) float slot_sh[128];   // this block's (b,s=jt) slot state
  __shared__ __align__(16) float gs[128], bs_[128];
  int t = threadIdx.x, bid = blockIdx.x;
  int b = bid >> 4, jt = bid & 15;
  bool isB = (jt < 8);
  unsigned* cA = cntA + (b << 6);
  unsigned* cB = cntB + (b << 6);

  if (t < 128) { gs[t] = g_in[t]; bs_[t] = be_in[t]; }
  if (isB) {
    if (t < 128) slot_sh[t] = slots_init[jt * 128 + t];
    q_project(sm.b, slot_sh, g_sl, be_sl, Wqk, bqk, wqbk, bqbk, qW_g, qb_g, b * 8 + jt);
    arrive(cB);
  }
  float4 pf[4];
  {
    const float* xsrc = x + (((long)b * NF_ + 0) * N_ + jt * 64) * D_;
#pragma unroll
    for (int i = 0; i < 4; ++i) {
      int ch = t + i * 512;
      pf[i] = *(const float4*)(xsrc + (ch >> 5) * 128 + (ch & 31) * 4);
    }
  }
  wait_for(cB, 8u);

  for (int it = 0; it < 17; ++it) {
    int f = (it == 0) ? 0 : it - 1;
    int wo = it > 0;
    // ================= phase A (all 256 blocks; per-batch tiles) =================
#pragma unroll
    for (int i = 0; i < 4; ++i) {
      int ch = t + i * 512;
      *(float4*)&sm.a.Xt[(ch >> 5) * 132 + (ch & 31) * 4] = pf[i];
    }
    sm.a.qWs[t] = gload(&qW_g[b * 1024 + t]);
    sm.a.qWs[512 + t] = gload(&qW_g[b * 1024 + 512 + t]);
    if (t < 8) sm.a.qbs[t] = gload(&qb_g[b * 8 + t]);
    __syncthreads();
    int r8 = t >> 3, p8 = t & 7;
    {
      const float4* row4 = (const float4*)(sm.a.Xt + r8 * 132 + p8 * 16);
      float s1 = 0.f, s2 = 0.f;
#pragma unroll
      for (int i = 0; i < 4; ++i) {
        float4 v = row4[i];
        s1 += v.x + v.y + v.z + v.w;
        s2 += v.x * v.x + v.y * v.y + v.z * v.z + v.w * v.w;
      }
      s1 += __shfl_down(s1, 1); s2 += __shfl_down(s2, 1);
      s1 += __shfl_down(s1, 2); s2 += __shfl_down(s2, 2);
      s1 += __shfl_down(s1, 4); s2 += __shfl_down(s2, 4);
      if (p8 == 0) { sm.a.rowsum[r8] = s1; sm.a.rowsum2[r8] = s2; }
    }
    __syncthreads();
    {
      float m = sm.a.rowsum[r8] * (1.f / 128.f);
      float var = sm.a.rowsum2[r8] * (1.f / 128.f) - m * m;
      float inv = rsqrtf(var + 1e-5f);
      float4* row4 = (float4*)(sm.a.Xt + r8 * 132 + p8 * 16);
      const float4* gg4 = (const float4*)(gs + p8 * 16);
      const float4* bb4 = (const float4*)(bs_ + p8 * 16);
#pragma unroll
      for (int i = 0; i < 4; ++i) {
        float4 v = row4[i], g4 = gg4[i], b4 = bb4[i];
        v.x = (v.x - m) * inv * g4.x + b4.x;
        v.y = (v.y - m) * inv * g4.y + b4.y;
        v.z = (v.z - m) * inv * g4.z + b4.z;
        v.w = (v.w - m) * inv * g4.w + b4.w;
        row4[i] = v;
      }
    }
    __syncthreads();
    {
      int s = t >> 6, j = t & 63;
      const float4* qq4 = (const float4*)(sm.a.qWs + s * 128);
      const float4* xr4 = (const float4*)(sm.a.Xt + j * 132);
      float d = 0.f;
#pragma unroll
      for (int k = 0; k < 32; ++k) {
        float4 xv = xr4[k], qv = qq4[k];
        d += xv.x * qv.x + xv.y * qv.y + xv.z * qv.z + xv.w * qv.w;
      }
      sm.a.at[s * 64 + j] = (d + sm.a.qbs[s]) * SCALE_;
    }
    __syncthreads();
    if (t < 64) {
      float vals[8], mx = -1e30f;
#pragma unroll
      for (int s = 0; s < 8; ++s) { vals[s] = sm.a.at[s * 64 + t]; mx = fmaxf(mx, vals[s]); }
      float sum = 0.f;
#pragma unroll
      for (int s = 0; s < 8; ++s) { vals[s] = __expf(vals[s] - mx); sum += vals[s]; }
      float rr = 1.f / sum;
#pragma unroll
      for (int s = 0; s < 8; ++s) { vals[s] = vals[s] * rr + 1e-8f; sm.a.at[s * 64 + t] = vals[s]; }
      if (wo) {
#pragma unroll
        for (int s = 0; s < 8; ++s)
          out_attn[(((long)b * NF_ + f) * S_ + s) * N_ + jt * 64 + t] = vals[s];
      }
    }
    __syncthreads();
    {
      int w = t >> 6, lane = t & 63;
      float v = sm.a.at[w * 64 + lane];
#pragma unroll
      for (int off = 32; off; off >>= 1) v += __shfl_down(v, off);
      if (lane == 0) gstore(&S_part[(b * 16 + jt) * 8 + w], v);
    }
    {
      int k2 = t & 127, h = t >> 7;
      float u0 = 0.f, u1 = 0.f;
      const float* a0 = sm.a.at + h * 64;
      const float* a1 = sm.a.at + (h + 4) * 64;
#pragma unroll
      for (int j0 = 0; j0 < 64; j0 += 4) {
        float4 av0 = *(const float4*)(a0 + j0);
        float4 av1 = *(const float4*)(a1 + j0);
        float x0 = sm.a.Xt[(j0 + 0) * 132 + k2];
        float x1 = sm.a.Xt[(j0 + 1) * 132 + k2];
        float x2 = sm.a.Xt[(j0 + 2) * 132 + k2];
        float x3 = sm.a.Xt[(j0 + 3) * 132 + k2];
        u0 += av0.x * x0 + av0.y * x1 + av0.z * x2 + av0.w * x3;
        u1 += av1.x * x0 + av1.y * x1 + av1.z * x2 + av1.w * x3;
      }
      float* pp = P_part + (long)(b * 16 + jt) * 8 * 128;
      gstore(&pp[h * 128 + k2], u0);
      gstore(&pp[(h + 4) * 128 + k2], u1);
    }
    arrive(cA);  // all 16 blocks of batch b announce P/S partials
    if (it < 16) {  // prefetch next frame tile (f(it+1) == it) while others compute
      const float* xsrc = x + (((long)b * NF_ + it) * N_ + jt * 64) * D_;
#pragma unroll
      for (int i = 0; i < 4; ++i) {
        int ch = t + i * 512;
        pf[i] = *(const float4*)(xsrc + (ch >> 5) * 128 + (ch & 31) * 4);
      }
    }
    // ================= phase B (blocks jt<8: slot s=jt of batch b) =================
    if (isB) {
      wait_for(cA, 16u * (it + 1));
      SmemB& Bm = sm.b;
      int s = jt;
      // stage 1: reduce P (t<128) while t>=128 compute gh = Whh@hprev + bhh (384 rows)
      if (t < 128) {
        float pa = 0.f;
#pragma unroll
        for (int j = 0; j < 16; ++j)
          pa += gload(&P_part[(long)((b * 16 + j) * 8 + s) * 128 + t]);
        Bm.Pk[t] = pa;
      } else {
        int r = t - 128;
        Bm.gh[r] = dot128f(Whh + r * 128, slot_sh, bhh[r]);
      }
      __syncthreads();
      // stage 2: giraw = Wiv@Pk (t<384, Wv stage folded away); S reduce on lanes of wave 7
      if (t < 384) {
        Bm.gi[t] = dot128f(Wiv + (long)t * 128, Bm.Pk, 0.f);
      } else if (t >= 448 && t < 464) {
        int tl = t - 448;
        float sv = gload(&S_part[(b * 16 + tl) * 8 + s]);
        sv += __shfl_down(sv, 8); sv += __shfl_down(sv, 4);
        sv += __shfl_down(sv, 2); sv += __shfl_down(sv, 1);
        if (tl == 0) Bm.ssm = sv;
      }
      __syncthreads();
      // stage 3: gates -> hn   (gi = giraw/ssm + bihv)
      if (t < 128) {
        float invss = 1.f / Bm.ssm;
        float gr = sigm(Bm.gi[t] * invss + bihv[t] + Bm.gh[t]);
        float gz = sigm(Bm.gi[128 + t] * invss + bihv[128 + t] + Bm.gh[128 + t]);
        float gn = tanh_f(Bm.gi[256 + t] * invss + bihv[256 + t] + gr * Bm.gh[256 + t]);
        Bm.hn[t] = (1.f - gz) * gn + gz * slot_sh[t];
      }
      // stage 4: LN_ff(hn) -> buf
      float m, inv;
      float hv = (t < 128) ? Bm.hn[t] : 0.f;  // stats128 syncs before cross-thread use
      stats128(hv, t, Bm.red, m, inv, 1e-5f);
      if (t < 128) Bm.buf[t] = (hv - m) * inv * g_ff[t] + be_ff[t];
      __syncthreads();
      // stage 5: hid = relu(W1@buf + b1)
      if (t < 128) Bm.hid[t] = fmaxf(dot128f(W1 + t * 128, Bm.buf, b1[t]), 0.f);
      __syncthreads();
      // stage 6: sn = hn + W2@hid + b2 -> slot_sh, out
      if (t < 128) {
        float ffv = dot128f(W2 + t * 128, Bm.hid, b2[t]);
        float sn = Bm.hn[t] + ffv;
        slot_sh[t] = sn;
        if (wo) out_slots[(((long)b * NF_ + f) * S_ + s) * D_ + t] = sn;
      }
      __syncthreads();
      // stage 7: next-frame q projection (Wqk fold), then announce
      if (it < 16) {
        q_project(Bm, slot_sh, g_sl, be_sl, Wqk, bqk, wqbk, bqbk, qW_g, qb_g, b * 8 + s);
        arrive(cB);
        wait_for(cB, 8u * (it + 2));
      }
    } else {
      if (it < 16) wait_for(cB, 8u * (it + 2));  // consumers of qW wait for the 8 producers
    }
  }
}

extern "C" void kernel_launch(void* const* d_in, const int* in_sizes, int n_in,
                              void* d_out, int out_size, void* d_ws, size_t ws_size,
                              hipStream_t stream) {
  const float* inputs     = (const float*)d_in[0];
  const float* slots_init = (const float*)d_in[1];
  const float* Wq  = (const float*)d_in[2];
  const float* bq  = (const float*)d_in[3];
  const float* Wk  = (const float*)d_in[4];
  const float* bk  = (const float*)d_in[5];
  const float* Wv  = (const float*)d_in[6];
  const float* bv  = (const float*)d_in[7];
  const float* W1  = (const float*)d_in[8];
  const float* b1  = (const float*)d_in[9];
  const float* W2  = (const float*)d_in[10];
  const float* b2  = (const float*)d_in[11];
  const float* Wih = (const float*)d_in[12];
  const float* Whh = (const float*)d_in[13];
  const float* bih = (const float*)d_in[14];
  const float* bhh = (const float*)d_in[15];
  const float* g_in  = (const float*)d_in[16];
  const float* be_in = (const float*)d_in[17];
  const float* g_sl  = (const float*)d_in[18];
  const float* be_sl = (const float*)d_in[19];
  const float* g_ff  = (const float*)d_in[20];
  const float* be_ff = (const float*)d_in[21];

  float* out_slots = (float*)d_out;
  float* out_attn  = out_slots + (size_t)B_ * NF_ * S_ * D_;

  char* ws = (char*)d_ws;
  unsigned* cntA = (unsigned*)ws;                    // 16 counters, 256 B apart
  unsigned* cntB = (unsigned*)(ws + 4096);
  float* Wiv   = (float*)(ws + 16384);               // 384x128 = 196608 -> ends 212992
  float* bihv  = (float*)(ws + 212992);              // 1536 -> 214528
  float* WqkW  = (float*)(ws + 214528);              // 65536 -> 280064
  float* bqk   = (float*)(ws + 280064);              // 512 -> 280576
  float* wqbk  = (float*)(ws + 280576);              // 512 -> 281088
  float* bqbk  = (float*)(ws + 281088);              // 256 -> 281344
  float* qW_g  = (float*)(ws + 281344);              // 65536 -> 346880
  float* qb_g  = (float*)(ws + 346880);              // 512 -> 347392
  float* P_part = (float*)(ws + 347392);             // 1 MB -> 1395968
  float* S_part = (float*)(ws + 1395968);            // 8 KB

  hipMemsetAsync(d_ws, 0, 16384, stream);  // zero counters (graph-capturable)

  precomp<<<512, 128, 0, stream>>>(Wih, bih, Wv, bv, Wq, bq, Wk, bk,
                                   Wiv, bihv, WqkW, bqk, wqbk, bqbk);
  slot_persist<<<NB, NT, 0, stream>>>(inputs, slots_init, Whh, bhh,
      W1, b1, W2, b2, g_in, be_in, g_sl, be_sl, g_ff, be_ff,
      Wiv, bihv, WqkW, bqk, wqbk, bqbk,
      out_slots, out_attn, cntA, cntB, qW_g, qb_g, P_part, S_part);
}

// Round 4
// 712.239 us; speedup vs baseline: 1.7016x; 1.0065x over previous
//
#include <hip/hip_runtime.h>

#define B_ 16
#define NF_ 16
#define N_ 1024
#define D_ 128
#define S_ 8
#define SCALE_ 0.08838834764831845f
#define NB 256
#define NT 512

struct SmemA {
  float Xt[64 * 128];       // RAW x tile, XOR-swizzled: (j,k4) -> j*128 + ((k4^(j&7))<<2)
  float at[8 * 64];         // dots, then attn (incl +eps)
  float gqWs[1024];         // g_in o qW, slot-major
  float mean[64], rinv[64];
  float c1s[8], c0s[8];
};
struct SmemB {              // phase-B scratch (separate from SmemA: no union -> overlap legal)
  float Pk[128];
  float gh[384];
  float gi[384];
  float hn[128], buf[128], hid[128], nrm[128];
  float red[16];
};

// ---- fence-free device-coherent accessors (proven in 612/550us kernels) ----
__device__ __forceinline__ float gload(const float* p) {
  return __hip_atomic_load(p, __ATOMIC_RELAXED, __HIP_MEMORY_SCOPE_AGENT);
}
__device__ __forceinline__ void gstore(float* p, float v) {
  __hip_atomic_store(p, v, __ATOMIC_RELAXED, __HIP_MEMORY_SCOPE_AGENT);
}
__device__ __forceinline__ void arrive(unsigned* c) {
  __syncthreads();
  if (threadIdx.x == 0) {
    __builtin_amdgcn_s_waitcnt(0);
    __hip_atomic_fetch_add(c, 1u, __ATOMIC_RELAXED, __HIP_MEMORY_SCOPE_AGENT);
  }
}
__device__ __forceinline__ void wait_for(unsigned* c, unsigned target) {
  if (threadIdx.x == 0) {
    while (__hip_atomic_load(c, __ATOMIC_RELAXED, __HIP_MEMORY_SCOPE_AGENT) < target)
      __builtin_amdgcn_s_sleep(1);
  }
  __syncthreads();
}

__device__ __forceinline__ float dot128f(const float* __restrict__ wrow, const float* x, float acc) {
  const float4* w = (const float4*)wrow;
#pragma unroll
  for (int i = 0; i < 32; ++i) {
    float4 v = w[i];
    const float4 xv = *(const float4*)(x + i * 4);
    acc += v.x * xv.x + v.y * xv.y + v.z * xv.z + v.w * xv.w;
  }
  return acc;
}

__device__ __forceinline__ void stats128(float v, int t, float* red, float& m, float& inv, float eps) {
  __syncthreads();
  float s = (t < 128) ? v : 0.f;
  float s2 = (t < 128) ? v * v : 0.f;
#pragma unroll
  for (int off = 32; off; off >>= 1) { s += __shfl_down(s, off); s2 += __shfl_down(s2, off); }
  if (t == 0)  { red[0] = s; red[2] = s2; }
  if (t == 64) { red[1] = s; red[3] = s2; }
  __syncthreads();
  m = (red[0] + red[1]) * (1.f / 128.f);
  float var = (red[2] + red[3]) * (1.f / 128.f) - m * m;
  inv = rsqrtf(var + 1e-5f);
}

__device__ __forceinline__ float sigm(float x) { return 1.f / (1.f + __expf(-x)); }
__device__ __forceinline__ float tanh_f(float x) { return 1.f - 2.f / (1.f + __expf(2.f * x)); }

// stage raw tile (swizzled) + per-row stats from registers (half-wave shfl_xor reduce).
// caller provides the barrier before first use (wait_for / syncthreads).
__device__ __forceinline__ void stage_stats(const float4* pf, float* Xt, float* mean, float* rinv, int t) {
  float s1[4], s2[4];
#pragma unroll
  for (int i = 0; i < 4; ++i) {
    int r = (t >> 5) + i * 16, kg = t & 31;
    *(float4*)&Xt[r * 128 + ((kg ^ (r & 7)) << 2)] = pf[i];
    s1[i] = pf[i].x + pf[i].y + pf[i].z + pf[i].w;
    s2[i] = pf[i].x * pf[i].x + pf[i].y * pf[i].y + pf[i].z * pf[i].z + pf[i].w * pf[i].w;
  }
#pragma unroll
  for (int mk = 16; mk; mk >>= 1) {
#pragma unroll
    for (int i = 0; i < 4; ++i) { s1[i] += __shfl_xor(s1[i], mk); s2[i] += __shfl_xor(s2[i], mk); }
  }
  if ((t & 31) == 0) {
#pragma unroll
    for (int i = 0; i < 4; ++i) {
      int r = (t >> 5) + i * 16;
      float mm = s1[i] * (1.f / 128.f);
      mean[r] = mm;
      rinv[r] = rsqrtf(s2[i] * (1.f / 128.f) - mm * mm + 1e-5f);
    }
  }
}

// slot -> LN_sl -> qW (Wqk fold) -> publish gqW = g_in o qW, c1 = sum(gqW), c0 = sum(bI*qW)+qb
__device__ void q_project_pub(SmemB& Bm, const float* slot,
    const float* __restrict__ g_sl, const float* __restrict__ be_sl,
    const float* __restrict__ Wqk, const float* __restrict__ bqk,
    const float* __restrict__ wqbk, const float* __restrict__ bqbk,
    const float* gI, const float* bI,
    float* gqW_g, float* cc_g, int b, int s, int t) {
  float m, inv;
  float sv = (t < 128) ? slot[t] : 0.f;
  stats128(sv, t, Bm.red, m, inv, 1e-5f);
  if (t < 128) Bm.nrm[t] = (sv - m) * inv * g_sl[t] + be_sl[t];
  __syncthreads();
  if (t < 128) {
    float qv = dot128f(Wqk + t * 128, Bm.nrm, bqk[t]);
    float gq = gI[t] * qv;
    gstore(&gqW_g[b * 1024 + s * 128 + t], gq);
    float r0 = gq, r1 = bI[t] * qv, r2 = wqbk[t] * Bm.nrm[t];
#pragma unroll
    for (int off = 32; off; off >>= 1) {
      r0 += __shfl_down(r0, off); r1 += __shfl_down(r1, off); r2 += __shfl_down(r2, off);
    }
    if ((t & 63) == 0) {
      int w = t >> 6;
      Bm.red[8 + w] = r0; Bm.red[10 + w] = r1; Bm.red[12 + w] = r2;
    }
  }
  __syncthreads();
  if (t == 0) {
    float c1 = Bm.red[8] + Bm.red[9];
    float qb = Bm.red[12] + Bm.red[13] + bqbk[0];
    float c0 = Bm.red[10] + Bm.red[11] + qb;
    gstore(&cc_g[b * 16 + s], c1);
    gstore(&cc_g[b * 16 + 8 + s], c0);
  }
}

// one-shot algebraic folds (verified rounds 1-3)
__global__ __launch_bounds__(128) void precomp(
    const float* __restrict__ Wih, const float* __restrict__ bih,
    const float* __restrict__ Wv, const float* __restrict__ bv,
    const float* __restrict__ Wq, const float* __restrict__ bq,
    const float* __restrict__ Wk, const float* __restrict__ bk,
    float* Wiv, float* bihv, float* Wqk, float* bqk, float* wqbk, float* bqbk) {
  __shared__ float r2[2];
  int r = blockIdx.x, t = threadIdx.x;
  if (r < 384) {
    float acc = 0.f;
#pragma unroll 8
    for (int k = 0; k < 128; ++k) acc += Wih[r * 128 + k] * Wv[k * 128 + t];
    Wiv[r * 128 + t] = acc;
    float p = Wih[r * 128 + t] * bv[t];
#pragma unroll
    for (int off = 32; off; off >>= 1) p += __shfl_down(p, off);
    if ((t & 63) == 0) r2[t >> 6] = p;
    __syncthreads();
    if (t == 0) bihv[r] = r2[0] + r2[1] + bih[r];
  } else {
    int c = r - 384;
    float acc = 0.f;
#pragma unroll 8
    for (int dd = 0; dd < 128; ++dd) acc += Wk[dd * 128 + c] * Wq[dd * 128 + t];
    Wqk[c * 128 + t] = acc;
    float p = Wk[t * 128 + c] * bq[t];
#pragma unroll
    for (int off = 32; off; off >>= 1) p += __shfl_down(p, off);
    if ((t & 63) == 0) r2[t >> 6] = p;
    __syncthreads();
    if (t == 0) bqk[c] = r2[0] + r2[1];
    if (c == 0) {
      float a2 = 0.f;
#pragma unroll 8
      for (int dd = 0; dd < 128; ++dd) a2 += Wq[dd * 128 + t] * bk[dd];
      wqbk[t] = a2;
      float p2 = bq[t] * bk[t];
#pragma unroll
      for (int off = 32; off; off >>= 1) p2 += __shfl_down(p2, off);
      __syncthreads();
      if ((t & 63) == 0) r2[t >> 6] = p2;
      __syncthreads();
      if (t == 0) bqbk[0] = r2[0] + r2[1];
    }
  }
}

__global__ __launch_bounds__(NT) void slot_persist(
    const float* __restrict__ x, const float* __restrict__ slots_init,
    const float* __restrict__ Whh, const float* __restrict__ bhh,
    const float* __restrict__ W1, const float* __restrict__ b1,
    const float* __restrict__ W2, const float* __restrict__ b2,
    const float* __restrict__ g_in, const float* __restrict__ be_in,
    const float* __restrict__ g_sl, const float* __restrict__ be_sl,
    const float* __restrict__ g_ff, const float* __restrict__ be_ff,
    const float* __restrict__ Wiv, const float* __restrict__ bihv,
    const float* __restrict__ Wqk, const float* __restrict__ bqk,
    const float* __restrict__ wqbk, const float* __restrict__ bqbk,
    float* out_slots, float* out_attn,
    unsigned* cntA, unsigned* cntB,
    float* U_g, float* SMB_g, float* gqW_g, float* cc_g) {
  __shared__ __align__(16) SmemA sa;
  __shared__ __align__(16) SmemB sb;
  __shared__ __align__(16) float slot_sh[128];
  __shared__ __align__(16) float gs[128], bs_[128];
  int t = threadIdx.x, bid = blockIdx.x;
  int b = bid >> 4, jt = bid & 15;
  bool isB = (jt < 8);
  unsigned* cA = cntA + (b << 6);
  unsigned* cB = cntB + (b << 6);
  int s = t >> 6, j = t & 63;

  if (t < 128) { gs[t] = g_in[t]; bs_[t] = be_in[t]; }
  __syncthreads();
  if (isB) {
    if (t < 128) slot_sh[t] = slots_init[jt * 128 + t];
    q_project_pub(sb, slot_sh, g_sl, be_sl, Wqk, bqk, wqbk, bqbk, gs, bs_,
                  gqW_g, cc_g, b, jt, t);
    arrive(cB);
  }
  float4 pf[4];
  {
    const float* xsrc = x + (((long)b * NF_ + 0) * N_ + jt * 64) * D_;
#pragma unroll
    for (int i = 0; i < 4; ++i) {
      int ch = t + i * 512;
      pf[i] = *(const float4*)(xsrc + (ch >> 5) * 128 + (ch & 31) * 4);
    }
  }
  stage_stats(pf, sa.Xt, sa.mean, sa.rinv, t);   // frame 0; barrier = loop-top wait_for

  for (int it = 0; it < 17; ++it) {
    int f = (it == 0) ? 0 : it - 1;
    int wo = it > 0;
    int par = it & 1;
    // ---- wait for qW of this frame; load folded q constants ----
    wait_for(cB, 8u * (it + 1));
    sa.gqWs[t] = gload(&gqW_g[b * 1024 + t]);
    sa.gqWs[512 + t] = gload(&gqW_g[b * 1024 + 512 + t]);
    if (t < 8) sa.c1s[t] = gload(&cc_g[b * 16 + t]);
    else if (t < 16) sa.c0s[t - 8] = gload(&cc_g[b * 16 + t]);
    __syncthreads();
    // ---- dots on RAW X with LN fold (conflict-free swizzled b128) ----
    {
      const float4* qq4 = (const float4*)(sa.gqWs + s * 128);
      float d = 0.f;
#pragma unroll
      for (int k4 = 0; k4 < 32; ++k4) {
        float4 xv = *(const float4*)&sa.Xt[j * 128 + ((k4 ^ (j & 7)) << 2)];
        float4 qv = qq4[k4];
        d += xv.x * qv.x + xv.y * qv.y + xv.z * qv.z + xv.w * qv.w;
      }
      float val = (d - sa.mean[j] * sa.c1s[s]) * sa.rinv[j] + sa.c0s[s];
      sa.at[s * 64 + j] = val * SCALE_;
    }
    __syncthreads();
    // ---- softmax over slots (per column j = t < 64) ----
    if (t < 64) {
      float vals[8], mx = -1e30f;
#pragma unroll
      for (int ss = 0; ss < 8; ++ss) { vals[ss] = sa.at[ss * 64 + t]; mx = fmaxf(mx, vals[ss]); }
      float sum = 0.f;
#pragma unroll
      for (int ss = 0; ss < 8; ++ss) { vals[ss] = __expf(vals[ss] - mx); sum += vals[ss]; }
      float rr = 1.f / sum;
#pragma unroll
      for (int ss = 0; ss < 8; ++ss) { vals[ss] = vals[ss] * rr + 1e-8f; sa.at[ss * 64 + t] = vals[ss]; }
      if (wo) {
#pragma unroll
        for (int ss = 0; ss < 8; ++ss)
          out_attn[(((long)b * NF_ + f) * S_ + ss) * N_ + jt * 64 + t] = vals[ss];
      }
    }
    __syncthreads();
    // ---- SS / MB partial sums (wave w = slot w), device atomics ----
    {
      float v = sa.at[s * 64 + j];
      float vm = v * sa.mean[j] * sa.rinv[j];
#pragma unroll
      for (int off = 32; off; off >>= 1) { v += __shfl_down(v, off); vm += __shfl_down(vm, off); }
      if (j == 0) {
        float* smb = SMB_g + (b * 2 + par) * 16;
        atomicAdd(&smb[s], v);
        atomicAdd(&smb[8 + s], vm);
      }
    }
    // ---- U partials: U[s][k] += sum_j attn*rinv*x  (raw X, fold) ----
    {
      int k2 = t & 127, h = t >> 7;
      int dg = k2 >> 2, dr = k2 & 3;
      float u0 = 0.f, u1 = 0.f;
      const float* a0 = sa.at + h * 64;
      const float* a1 = sa.at + (h + 4) * 64;
#pragma unroll
      for (int j0 = 0; j0 < 64; j0 += 4) {
        float4 av0 = *(const float4*)(a0 + j0);
        float4 av1 = *(const float4*)(a1 + j0);
        float4 rv = *(const float4*)(sa.rinv + j0);
        float x0 = sa.Xt[(j0 + 0) * 128 + ((dg ^ ((j0 + 0) & 7)) << 2) + dr];
        float x1 = sa.Xt[(j0 + 1) * 128 + ((dg ^ ((j0 + 1) & 7)) << 2) + dr];
        float x2 = sa.Xt[(j0 + 2) * 128 + ((dg ^ ((j0 + 2) & 7)) << 2) + dr];
        float x3 = sa.Xt[(j0 + 3) * 128 + ((dg ^ ((j0 + 3) & 7)) << 2) + dr];
        float rx0 = rv.x * x0, rx1 = rv.y * x1, rx2 = rv.z * x2, rx3 = rv.w * x3;
        u0 += av0.x * rx0 + av0.y * rx1 + av0.z * rx2 + av0.w * rx3;
        u1 += av1.x * rx0 + av1.y * rx1 + av1.z * rx2 + av1.w * rx3;
      }
      float* Ub = U_g + ((b * 2 + par) << 10);
      atomicAdd(&Ub[h * 128 + k2], u0);
      atomicAdd(&Ub[(h + 4) * 128 + k2], u1);
    }
    arrive(cA);
    // ================= phase B (blocks jt<8: slot s=jt of batch b) =================
    if (isB) {
      wait_for(cA, 16u * (it + 1));
      int sl = jt;
      float* Ub = U_g + ((b * 2 + par) << 10);
      float* smb = SMB_g + (b * 2 + par) * 16;
      // stage 1: read U (t<128) | gh = Whh@hprev + bhh (t>=128)
      if (t < 128) {
        sb.Pk[t] = gload(&Ub[sl * 128 + t]);
        if (t == 0) {
          sb.red[14] = gload(&smb[sl]);       // SS
          sb.red[15] = gload(&smb[8 + sl]);   // MB
        }
      } else {
        int r = t - 128;
        sb.gh[r] = dot128f(Whh + r * 128, slot_sh, bhh[r]);
      }
      __syncthreads();
      float ssv = sb.red[14], mbv = sb.red[15];
      // stage 2: Pk = gI*(U - MB) + bI*SS ; zero accumulators for reuse at it+2
      if (t < 128) {
        sb.Pk[t] = gs[t] * (sb.Pk[t] - mbv) + bs_[t] * ssv;
        gstore(&Ub[sl * 128 + t], 0.f);
        if (t == 0) { gstore(&smb[sl], 0.f); gstore(&smb[8 + sl], 0.f); }
      }
      __syncthreads();
      // stage 3: gi_raw = Wiv @ Pk   (Wv fold)
      if (t < 384) sb.gi[t] = dot128f(Wiv + (long)t * 128, sb.Pk, 0.f);
      __syncthreads();
      // stage 4: gates -> hn  (gi = gi_raw/SS + bihv)
      float hnew = 0.f;
      if (t < 128) {
        float invss = 1.f / ssv;
        float gr = sigm(sb.gi[t] * invss + bihv[t] + sb.gh[t]);
        float gz = sigm(sb.gi[128 + t] * invss + bihv[128 + t] + sb.gh[128 + t]);
        float gn = tanh_f(sb.gi[256 + t] * invss + bihv[256 + t] + gr * sb.gh[256 + t]);
        hnew = (1.f - gz) * gn + gz * slot_sh[t];
        sb.hn[t] = hnew;
      }
      // stage 5: LN_ff(hn) -> buf
      float m, inv;
      stats128(hnew, t, sb.red, m, inv, 1e-5f);
      if (t < 128) sb.buf[t] = (hnew - m) * inv * g_ff[t] + be_ff[t];
      __syncthreads();
      // stage 6: hid = relu(W1@buf + b1)
      if (t < 128) sb.hid[t] = fmaxf(dot128f(W1 + t * 128, sb.buf, b1[t]), 0.f);
      __syncthreads();
      // stage 7: sn = hn + W2@hid + b2
      if (t < 128) {
        float ffv = dot128f(W2 + t * 128, sb.hid, b2[t]);
        float sn = sb.hn[t] + ffv;
        slot_sh[t] = sn;
        if (wo) out_slots[(((long)b * NF_ + f) * S_ + sl) * D_ + t] = sn;
      }
      __syncthreads();
      // stage 8: next-frame q projection + announce
      if (it < 16) {
        q_project_pub(sb, slot_sh, g_sl, be_sl, Wqk, bqk, wqbk, bqbk, gs, bs_,
                      gqW_g, cc_g, b, sl, t);
        arrive(cB);
      }
    }
    // ---- prefetch + stage next frame tile (hidden under B-chain for non-B) ----
    if (it < 16) {
      const float* xsrc = x + (((long)b * NF_ + it) * N_ + jt * 64) * D_;
#pragma unroll
      for (int i = 0; i < 4; ++i) {
        int ch = t + i * 512;
        pf[i] = *(const float4*)(xsrc + (ch >> 5) * 128 + (ch & 31) * 4);
      }
      stage_stats(pf, sa.Xt, sa.mean, sa.rinv, t);   // barrier = next wait_for
    }
  }
}

extern "C" void kernel_launch(void* const* d_in, const int* in_sizes, int n_in,
                              void* d_out, int out_size, void* d_ws, size_t ws_size,
                              hipStream_t stream) {
  const float* inputs     = (const float*)d_in[0];
  const float* slots_init = (const float*)d_in[1];
  const float* Wq  = (const float*)d_in[2];
  const float* bq  = (const float*)d_in[3];
  const float* Wk  = (const float*)d_in[4];
  const float* bk  = (const float*)d_in[5];
  const float* Wv  = (const float*)d_in[6];
  const float* bv  = (const float*)d_in[7];
  const float* W1  = (const float*)d_in[8];
  const float* b1  = (const float*)d_in[9];
  const float* W2  = (const float*)d_in[10];
  const float* b2  = (const float*)d_in[11];
  const float* Wih = (const float*)d_in[12];
  const float* Whh = (const float*)d_in[13];
  const float* bih = (const float*)d_in[14];
  const float* bhh = (const float*)d_in[15];
  const float* g_in  = (const float*)d_in[16];
  const float* be_in = (const float*)d_in[17];
  const float* g_sl  = (const float*)d_in[18];
  const float* be_sl = (const float*)d_in[19];
  const float* g_ff  = (const float*)d_in[20];
  const float* be_ff = (const float*)d_in[21];

  float* out_slots = (float*)d_out;
  float* out_attn  = out_slots + (size_t)B_ * NF_ * S_ * D_;

  char* ws = (char*)d_ws;
  unsigned* cntA = (unsigned*)ws;                    // 16 counters, 256 B apart (4 KB)
  unsigned* cntB = (unsigned*)(ws + 4096);           // 4 KB
  float* U_g   = (float*)(ws + 8192);                // [16][2][1024] = 131072 -> 139264
  float* SMB_g = (float*)(ws + 139264);              // [16][2][16]   = 2048   -> 141312
  float* Wiv   = (float*)(ws + 141312);              // 196608 -> 337920
  float* bihv  = (float*)(ws + 337920);              // 1536   -> 339456
  float* WqkW  = (float*)(ws + 339456);              // 65536  -> 404992
  float* bqk   = (float*)(ws + 404992);              // 512    -> 405504
  float* wqbk  = (float*)(ws + 405504);              // 512    -> 406016
  float* bqbk  = (float*)(ws + 406016);              // 256    -> 406272
  float* gqW_g = (float*)(ws + 406272);              // 65536  -> 471808
  float* cc_g  = (float*)(ws + 471808);              // 1024   -> 472832

  // zero counters + U/SMB accumulators (kernel leaves them re-zeroed; this covers 1st launch)
  hipMemsetAsync(d_ws, 0, 141312, stream);

  precomp<<<512, 128, 0, stream>>>(Wih, bih, Wv, bv, Wq, bq, Wk, bk,
                                   Wiv, bihv, WqkW, bqk, wqbk, bqbk);
  slot_persist<<<NB, NT, 0, stream>>>(inputs, slots_init, Whh, bhh,
      W1, b1, W2, b2, g_in, be_in, g_sl, be_sl, g_ff, be_ff,
      Wiv, bihv, WqkW, bqk, wqbk, bqbk,
      out_slots, out_attn, cntA, cntB, U_g, SMB_g, gqW_g, cc_g);
}

// Round 5
// 663.299 us; speedup vs baseline: 1.8272x; 1.0738x over previous
//
#include <hip/hip_runtime.h>

#define B_ 16
#define NF_ 16
#define N_ 1024
#define D_ 128
#define S_ 8
#define SCALE_ 0.08838834764831845f
#define NB 256
#define NT 512
// scalar index into chunk-padded [4][36] vectors (chunk c = i>>5 at offset c*36)
#define CPAD(i) ((((i) >> 5) * 36) + ((i) & 31))

struct SmemA {
  float Xt[64 * 128];       // NORMALIZED x-hat, XOR-swizzled: (j,k4) -> j*128 + ((k4^(j&7))<<2)
  float at[8 * 64];         // dots, then attn (incl +eps)
  float qWs[1024];          // SCALE-prefolded qW, slot-major
  float qbs[8];
};
struct SmemB {              // phase-B scratch (separate structs: A/B overlap legal)
  float Uk[144];            // chunk-padded U vector
  float gh[384];
  float gi[384];
  float hn[128];
  float buf[144], hid[144], nrm[144];   // chunk-padded matvec operands
  float red[16];
};

// ---- fence-free device-coherent accessors (proven across 612/550/539us kernels) ----
__device__ __forceinline__ float gload(const float* p) {
  return __hip_atomic_load(p, __ATOMIC_RELAXED, __HIP_MEMORY_SCOPE_AGENT);
}
__device__ __forceinline__ void gstore(float* p, float v) {
  __hip_atomic_store(p, v, __ATOMIC_RELAXED, __HIP_MEMORY_SCOPE_AGENT);
}
__device__ __forceinline__ void arrive(unsigned* c) {
  __syncthreads();
  if (threadIdx.x == 0) {
    __builtin_amdgcn_s_waitcnt(0);
    __hip_atomic_fetch_add(c, 1u, __ATOMIC_RELAXED, __HIP_MEMORY_SCOPE_AGENT);
  }
}
__device__ __forceinline__ void wait_for(unsigned* c, unsigned target) {
  if (threadIdx.x == 0) {
    while (__hip_atomic_load(c, __ATOMIC_RELAXED, __HIP_MEMORY_SCOPE_AGENT) < target)
      __builtin_amdgcn_s_sleep(1);
  }
  __syncthreads();
}

__device__ __forceinline__ float dot128f(const float* __restrict__ wrow, const float* x, float acc) {
  const float4* w = (const float4*)wrow;
#pragma unroll
  for (int i = 0; i < 32; ++i) {
    float4 v = w[i];
    const float4 xv = *(const float4*)(x + i * 4);
    acc += v.x * xv.x + v.y * xv.y + v.z * xv.z + v.w * xv.w;
  }
  return acc;
}

__device__ __forceinline__ void stats128(float v, int t, float* red, float& m, float& inv, float eps) {
  __syncthreads();
  float s = (t < 128) ? v : 0.f;
  float s2 = (t < 128) ? v * v : 0.f;
#pragma unroll
  for (int off = 32; off; off >>= 1) { s += __shfl_down(s, off); s2 += __shfl_down(s2, off); }
  if (t == 0)  { red[0] = s; red[2] = s2; }
  if (t == 64) { red[1] = s; red[3] = s2; }
  __syncthreads();
  m = (red[0] + red[1]) * (1.f / 128.f);
  float var = (red[2] + red[3]) * (1.f / 128.f) - m * m;
  inv = rsqrtf(var + 1e-5f);
}

__device__ __forceinline__ float sigm(float x) { return 1.f / (1.f + __expf(-x)); }
__device__ __forceinline__ float tanh_f(float x) { return 1.f - 2.f / (1.f + __expf(2.f * x)); }

// stage NORMALIZED tile (swizzled): per-row stats via 32-lane butterfly (all lanes get
// the sums), LN applied in registers, x-hat written once. Runs in the prefetch window.
__device__ __forceinline__ void stage_norm(const float4* pf, float* Xt,
                                           float4 g4, float4 b4, int t) {
  float s1[4], s2[4];
#pragma unroll
  for (int i = 0; i < 4; ++i) {
    s1[i] = pf[i].x + pf[i].y + pf[i].z + pf[i].w;
    s2[i] = pf[i].x * pf[i].x + pf[i].y * pf[i].y + pf[i].z * pf[i].z + pf[i].w * pf[i].w;
  }
#pragma unroll
  for (int mk = 16; mk; mk >>= 1) {
#pragma unroll
    for (int i = 0; i < 4; ++i) { s1[i] += __shfl_xor(s1[i], mk); s2[i] += __shfl_xor(s2[i], mk); }
  }
  int kg = t & 31;
#pragma unroll
  for (int i = 0; i < 4; ++i) {
    int r = (t >> 5) + i * 16;
    float m = s1[i] * (1.f / 128.f);
    float inv = rsqrtf(s2[i] * (1.f / 128.f) - m * m + 1e-5f);
    float4 v = pf[i];
    v.x = (v.x - m) * inv * g4.x + b4.x;
    v.y = (v.y - m) * inv * g4.y + b4.y;
    v.z = (v.z - m) * inv * g4.z + b4.z;
    v.w = (v.w - m) * inv * g4.w + b4.w;
    *(float4*)&Xt[r * 128 + ((kg ^ (r & 7)) << 2)] = v;
  }
}

// slot -> LN_sl -> qW = SCALE*(Wqk@nrm + bqk), qb = SCALE*(wqbk.nrm + bqbk); k-split matvec
__device__ void q_project_pub(SmemB& Bm, const float* slot,
    const float* __restrict__ g_sl, const float* __restrict__ be_sl,
    const float* __restrict__ Wqk, const float* __restrict__ bqk,
    const float* __restrict__ wqbk, const float* __restrict__ bqbk,
    float* qW_g, float* qb_g, int b, int sl, int t) {
  float m, inv;
  float sv = (t < 128) ? slot[t] : 0.f;
  stats128(sv, t, Bm.red, m, inv, 1e-5f);
  if (t < 128) {
    float nv = (sv - m) * inv * g_sl[t] + be_sl[t];
    Bm.nrm[CPAD(t)] = nv;
    float qp = wqbk[t] * nv;
#pragma unroll
    for (int off = 32; off; off >>= 1) qp += __shfl_down(qp, off);
    if (t == 0)  Bm.red[4] = qp;
    if (t == 64) Bm.red[5] = qp;
  }
  __syncthreads();
  {
    int c = t & 3, r = t >> 2;
    const float4* wr = (const float4*)(Wqk + r * 128 + c * 32);
    float acc = 0.f;
#pragma unroll
    for (int q = 0; q < 8; ++q) {
      float4 wv = wr[q];
      float4 vv = *(const float4*)&Bm.nrm[c * 36 + q * 4];
      acc += wv.x * vv.x + wv.y * vv.y + wv.z * vv.z + wv.w * vv.w;
    }
    acc += __shfl_down(acc, 2); acc += __shfl_down(acc, 1);
    if (c == 0) gstore(&qW_g[b * 1024 + sl * 128 + r], (acc + bqk[r]) * SCALE_);
  }
  if (t == 0) gstore(&qb_g[b * 8 + sl], (Bm.red[4] + Bm.red[5] + bqbk[0]) * SCALE_);
}

// one-shot algebraic folds (harness-verified rounds 1-4)
__global__ __launch_bounds__(128) void precomp(
    const float* __restrict__ Wih, const float* __restrict__ bih,
    const float* __restrict__ Wv, const float* __restrict__ bv,
    const float* __restrict__ Wq, const float* __restrict__ bq,
    const float* __restrict__ Wk, const float* __restrict__ bk,
    float* Wiv, float* bihv, float* Wqk, float* bqk, float* wqbk, float* bqbk) {
  __shared__ float r2[2];
  int r = blockIdx.x, t = threadIdx.x;
  if (r < 384) {
    float acc = 0.f;
#pragma unroll 8
    for (int k = 0; k < 128; ++k) acc += Wih[r * 128 + k] * Wv[k * 128 + t];
    Wiv[r * 128 + t] = acc;
    float p = Wih[r * 128 + t] * bv[t];
#pragma unroll
    for (int off = 32; off; off >>= 1) p += __shfl_down(p, off);
    if ((t & 63) == 0) r2[t >> 6] = p;
    __syncthreads();
    if (t == 0) bihv[r] = r2[0] + r2[1] + bih[r];
  } else {
    int c = r - 384;
    float acc = 0.f;
#pragma unroll 8
    for (int dd = 0; dd < 128; ++dd) acc += Wk[dd * 128 + c] * Wq[dd * 128 + t];
    Wqk[c * 128 + t] = acc;
    float p = Wk[t * 128 + c] * bq[t];
#pragma unroll
    for (int off = 32; off; off >>= 1) p += __shfl_down(p, off);
    if ((t & 63) == 0) r2[t >> 6] = p;
    __syncthreads();
    if (t == 0) bqk[c] = r2[0] + r2[1];
    if (c == 0) {
      float a2 = 0.f;
#pragma unroll 8
      for (int dd = 0; dd < 128; ++dd) a2 += Wq[dd * 128 + t] * bk[dd];
      wqbk[t] = a2;
      float p2 = bq[t] * bk[t];
#pragma unroll
      for (int off = 32; off; off >>= 1) p2 += __shfl_down(p2, off);
      __syncthreads();
      if ((t & 63) == 0) r2[t >> 6] = p2;
      __syncthreads();
      if (t == 0) bqbk[0] = r2[0] + r2[1];
    }
  }
}

__global__ __launch_bounds__(NT) void slot_persist(
    const float* __restrict__ x, const float* __restrict__ slots_init,
    const float* __restrict__ Whh, const float* __restrict__ bhh,
    const float* __restrict__ W1, const float* __restrict__ b1,
    const float* __restrict__ W2, const float* __restrict__ b2,
    const float* __restrict__ g_in, const float* __restrict__ be_in,
    const float* __restrict__ g_sl, const float* __restrict__ be_sl,
    const float* __restrict__ g_ff, const float* __restrict__ be_ff,
    const float* __restrict__ Wiv, const float* __restrict__ bihv,
    const float* __restrict__ Wqk, const float* __restrict__ bqk,
    const float* __restrict__ wqbk, const float* __restrict__ bqbk,
    float* out_slots, float* out_attn,
    unsigned* cntA, unsigned* cntB,
    float* U_g, float* SS_g, float* qW_g, float* qb_g) {
  __shared__ __align__(16) SmemA sa;
  __shared__ __align__(16) SmemB sb;
  __shared__ __align__(16) float slot_sh[128];
  int t = threadIdx.x, bid = blockIdx.x;
  int b = bid >> 4, jt = bid & 15;
  bool isB = (jt < 8);
  unsigned* cA = cntA + (b << 6);
  unsigned* cB = cntB + (b << 6);
  int s = t >> 6, j = t & 63;

  // per-thread LN_in constants for this thread's staged columns (kg = t&31, same all rows)
  const float4 g4 = *(const float4*)(g_in + (t & 31) * 4);
  const float4 b4 = *(const float4*)(be_in + (t & 31) * 4);

  if (isB) {
    if (t < 128) slot_sh[t] = slots_init[jt * 128 + t];
    q_project_pub(sb, slot_sh, g_sl, be_sl, Wqk, bqk, wqbk, bqbk, qW_g, qb_g, b, jt, t);
    arrive(cB);
  }
  float4 pf[4];
  {
    const float* xsrc = x + (((long)b * NF_ + 0) * N_ + jt * 64) * D_;
#pragma unroll
    for (int i = 0; i < 4; ++i) {
      int ch = t + i * 512;
      pf[i] = *(const float4*)(xsrc + (ch >> 5) * 128 + (ch & 31) * 4);
    }
  }
  stage_norm(pf, sa.Xt, g4, b4, t);   // frame 0; barrier = loop-top wait_for

  for (int it = 0; it < 17; ++it) {
    int f = (it == 0) ? 0 : it - 1;
    int wo = it > 0;
    int par = it & 1;
    // ---- wait for qW of this frame ----
    wait_for(cB, 8u * (it + 1));
    sa.qWs[t] = gload(&qW_g[b * 1024 + t]);
    sa.qWs[512 + t] = gload(&qW_g[b * 1024 + 512 + t]);
    if (t < 8) sa.qbs[t] = gload(&qb_g[b * 8 + t]);
    __syncthreads();
    // ---- dots on normalized X (conflict-free swizzled b128); SCALE prefolded ----
    {
      const float4* qq4 = (const float4*)(sa.qWs + s * 128);
      float d = 0.f;
#pragma unroll
      for (int k4 = 0; k4 < 32; ++k4) {
        float4 xv = *(const float4*)&sa.Xt[j * 128 + ((k4 ^ (j & 7)) << 2)];
        float4 qv = qq4[k4];
        d += xv.x * qv.x + xv.y * qv.y + xv.z * qv.z + xv.w * qv.w;
      }
      sa.at[s * 64 + j] = d + sa.qbs[s];
    }
    __syncthreads();
    // ---- softmax over slots (per column j = t < 64); stores deferred ----
    float vals[8];
    if (t < 64) {
      float mx = -1e30f;
#pragma unroll
      for (int ss = 0; ss < 8; ++ss) { vals[ss] = sa.at[ss * 64 + t]; mx = fmaxf(mx, vals[ss]); }
      float sum = 0.f;
#pragma unroll
      for (int ss = 0; ss < 8; ++ss) { vals[ss] = __expf(vals[ss] - mx); sum += vals[ss]; }
      float rr = 1.f / sum;
#pragma unroll
      for (int ss = 0; ss < 8; ++ss) { vals[ss] = vals[ss] * rr + 1e-8f; sa.at[ss * 64 + t] = vals[ss]; }
    }
    __syncthreads();
    // ---- SS partials (wave = slot), device atomics ----
    {
      float v = sa.at[s * 64 + j];
#pragma unroll
      for (int off = 32; off; off >>= 1) v += __shfl_down(v, off);
      if (j == 0) atomicAdd(&SS_g[(b * 2 + par) * 8 + s], v);
    }
    // ---- U partials: U[s][k] += sum_j attn * xhat ----
    {
      int k2 = t & 127, h = t >> 7;
      int dg = k2 >> 2, dr = k2 & 3;
      float u0 = 0.f, u1 = 0.f;
      const float* a0 = sa.at + h * 64;
      const float* a1 = sa.at + (h + 4) * 64;
#pragma unroll
      for (int j0 = 0; j0 < 64; j0 += 4) {
        float4 av0 = *(const float4*)(a0 + j0);
        float4 av1 = *(const float4*)(a1 + j0);
        float x0 = sa.Xt[(j0 + 0) * 128 + ((dg ^ ((j0 + 0) & 7)) << 2) + dr];
        float x1 = sa.Xt[(j0 + 1) * 128 + ((dg ^ ((j0 + 1) & 7)) << 2) + dr];
        float x2 = sa.Xt[(j0 + 2) * 128 + ((dg ^ ((j0 + 2) & 7)) << 2) + dr];
        float x3 = sa.Xt[(j0 + 3) * 128 + ((dg ^ ((j0 + 3) & 7)) << 2) + dr];
        u0 += av0.x * x0 + av0.y * x1 + av0.z * x2 + av0.w * x3;
        u1 += av1.x * x0 + av1.y * x1 + av1.z * x2 + av1.w * x3;
      }
      float* Ub = U_g + ((b * 2 + par) << 10);
      atomicAdd(&Ub[h * 128 + k2], u0);
      atomicAdd(&Ub[(h + 4) * 128 + k2], u1);
    }
    arrive(cA);
    // ---- deferred attn stores (latency hides under B-chain / prefetch) ----
    if (wo && t < 64) {
#pragma unroll
      for (int ss = 0; ss < 8; ++ss)
        out_attn[(((long)b * NF_ + f) * S_ + ss) * N_ + jt * 64 + t] = vals[ss];
    }
    // ================= phase B (blocks jt<8: slot s=jt of batch b) =================
    if (isB) {
      wait_for(cA, 16u * (it + 1));
      int sl = jt;
      float* Ub = U_g + ((b * 2 + par) << 10) + sl * 128;
      float* ssb = SS_g + (b * 2 + par) * 8;
      // stage 1: read U + SS, zero them (t<128) | gh = Whh@hprev + bhh (t>=128)
      if (t < 128) {
        float uv = gload(&Ub[t]);
        sb.Uk[CPAD(t)] = uv;
        gstore(&Ub[t], 0.f);
        if (t == 0) { sb.red[14] = gload(&ssb[sl]); gstore(&ssb[sl], 0.f); }
      } else {
        int r = t - 128;
        sb.gh[r] = dot128f(Whh + (long)r * 128, slot_sh, bhh[r]);
      }
      __syncthreads();
      // stage 2: gi_raw = Wiv @ U   (k-split: 512 threads, 3 rows each, shfl reduce)
      {
        int c = t & 3, rb = t >> 2;
        float4 uv[8];
#pragma unroll
        for (int q = 0; q < 8; ++q) uv[q] = *(const float4*)&sb.Uk[c * 36 + q * 4];
#pragma unroll
        for (int g = 0; g < 3; ++g) {
          int r = rb + g * 128;
          const float4* wr = (const float4*)(Wiv + (long)r * 128 + c * 32);
          float acc = 0.f;
#pragma unroll
          for (int q = 0; q < 8; ++q) {
            float4 wv = wr[q];
            acc += wv.x * uv[q].x + wv.y * uv[q].y + wv.z * uv[q].z + wv.w * uv[q].w;
          }
          acc += __shfl_down(acc, 2); acc += __shfl_down(acc, 1);
          if (c == 0) sb.gi[r] = acc;
        }
      }
      __syncthreads();
      // stage 3: gates -> hn   (gi = gi_raw/SS + bihv)
      float hnew = 0.f;
      if (t < 128) {
        float invss = 1.f / sb.red[14];
        float gr = sigm(sb.gi[t] * invss + bihv[t] + sb.gh[t]);
        float gz = sigm(sb.gi[128 + t] * invss + bihv[128 + t] + sb.gh[128 + t]);
        float gn = tanh_f(sb.gi[256 + t] * invss + bihv[256 + t] + gr * sb.gh[256 + t]);
        hnew = (1.f - gz) * gn + gz * slot_sh[t];
        sb.hn[t] = hnew;
      }
      // stage 4: LN_ff(hn) -> buf (chunk-padded)
      float m, inv;
      stats128(hnew, t, sb.red, m, inv, 1e-5f);
      if (t < 128) sb.buf[CPAD(t)] = (hnew - m) * inv * g_ff[t] + be_ff[t];
      __syncthreads();
      // stage 5: hid = relu(W1@buf + b1)  (k-split)
      {
        int c = t & 3, r = t >> 2;
        const float4* wr = (const float4*)(W1 + r * 128 + c * 32);
        float acc = 0.f;
#pragma unroll
        for (int q = 0; q < 8; ++q) {
          float4 wv = wr[q];
          float4 vv = *(const float4*)&sb.buf[c * 36 + q * 4];
          acc += wv.x * vv.x + wv.y * vv.y + wv.z * vv.z + wv.w * vv.w;
        }
        acc += __shfl_down(acc, 2); acc += __shfl_down(acc, 1);
        if (c == 0) sb.hid[CPAD(r)] = fmaxf(acc + b1[r], 0.f);
      }
      __syncthreads();
      // stage 6: sn = hn + W2@hid + b2  (k-split) -> slot_sh
      {
        int c = t & 3, r = t >> 2;
        const float4* wr = (const float4*)(W2 + r * 128 + c * 32);
        float acc = 0.f;
#pragma unroll
        for (int q = 0; q < 8; ++q) {
          float4 wv = wr[q];
          float4 vv = *(const float4*)&sb.hid[c * 36 + q * 4];
          acc += wv.x * vv.x + wv.y * vv.y + wv.z * vv.z + wv.w * vv.w;
        }
        acc += __shfl_down(acc, 2); acc += __shfl_down(acc, 1);
        if (c == 0) slot_sh[r] = sb.hn[r] + acc + b2[r];
      }
      // stage 7: next-frame q projection (starts with internal barrier) + announce
      if (it < 16) {
        q_project_pub(sb, slot_sh, g_sl, be_sl, Wqk, bqk, wqbk, bqbk, qW_g, qb_g, b, sl, t);
        arrive(cB);
      } else {
        __syncthreads();
      }
      // deferred slots store (latency hides under next A-phase)
      if (wo && t < 128)
        out_slots[(((long)b * NF_ + f) * S_ + sl) * D_ + t] = slot_sh[t];
    }
    // ---- prefetch + stage next frame (it==0 reuses frame 0 already staged) ----
    if (it && it < 16) {
      const float* xsrc = x + (((long)b * NF_ + it) * N_ + jt * 64) * D_;
#pragma unroll
      for (int i = 0; i < 4; ++i) {
        int ch = t + i * 512;
        pf[i] = *(const float4*)(xsrc + (ch >> 5) * 128 + (ch & 31) * 4);
      }
      stage_norm(pf, sa.Xt, g4, b4, t);   // barrier = next loop-top wait_for
    }
  }
}

extern "C" void kernel_launch(void* const* d_in, const int* in_sizes, int n_in,
                              void* d_out, int out_size, void* d_ws, size_t ws_size,
                              hipStream_t stream) {
  const float* inputs     = (const float*)d_in[0];
  const float* slots_init = (const float*)d_in[1];
  const float* Wq  = (const float*)d_in[2];
  const float* bq  = (const float*)d_in[3];
  const float* Wk  = (const float*)d_in[4];
  const float* bk  = (const float*)d_in[5];
  const float* Wv  = (const float*)d_in[6];
  const float* bv  = (const float*)d_in[7];
  const float* W1  = (const float*)d_in[8];
  const float* b1  = (const float*)d_in[9];
  const float* W2  = (const float*)d_in[10];
  const float* b2  = (const float*)d_in[11];
  const float* Wih = (const float*)d_in[12];
  const float* Whh = (const float*)d_in[13];
  const float* bih = (const float*)d_in[14];
  const float* bhh = (const float*)d_in[15];
  const float* g_in  = (const float*)d_in[16];
  const float* be_in = (const float*)d_in[17];
  const float* g_sl  = (const float*)d_in[18];
  const float* be_sl = (const float*)d_in[19];
  const float* g_ff  = (const float*)d_in[20];
  const float* be_ff = (const float*)d_in[21];

  float* out_slots = (float*)d_out;
  float* out_attn  = out_slots + (size_t)B_ * NF_ * S_ * D_;

  char* ws = (char*)d_ws;
  unsigned* cntA = (unsigned*)ws;                    // 16 counters, 256 B apart (4 KB)
  unsigned* cntB = (unsigned*)(ws + 4096);           // 4 KB
  float* U_g   = (float*)(ws + 8192);                // [16][2][1024] = 131072 -> 139264
  float* SS_g  = (float*)(ws + 139264);              // [16][2][8]    = 1024   -> 140288
  float* Wiv   = (float*)(ws + 140288);              // 196608 -> 336896
  float* bihv  = (float*)(ws + 336896);              // 1536   -> 338432
  float* WqkW  = (float*)(ws + 338432);              // 65536  -> 403968
  float* bqk   = (float*)(ws + 403968);              // 512    -> 404480
  float* wqbk  = (float*)(ws + 404480);              // 512    -> 404992
  float* bqbk  = (float*)(ws + 404992);              // 256    -> 405248
  float* qW_g  = (float*)(ws + 405248);              // 65536  -> 470784
  float* qb_g  = (float*)(ws + 470784);              // 512    -> 471296

  // zero counters + U/SS accumulators (kernel leaves them re-zeroed after use)
  hipMemsetAsync(d_ws, 0, 140288, stream);

  precomp<<<512, 128, 0, stream>>>(Wih, bih, Wv, bv, Wq, bq, Wk, bk,
                                   Wiv, bihv, WqkW, bqk, wqbk, bqbk);
  slot_persist<<<NB, NT, 0, stream>>>(inputs, slots_init, Whh, bhh,
      W1, b1, W2, b2, g_in, be_in, g_sl, be_sl, g_ff, be_ff,
      Wiv, bihv, WqkW, bqk, wqbk, bqbk,
      out_slots, out_attn, cntA, cntB, U_g, SS_g, qW_g, qb_g);
}